// Round 1
// baseline (390.500 us; speedup 1.0000x reference)
//
#include <hip/hip_runtime.h>
#include <hip/hip_bf16.h>

#define Bd 16
#define Td 1500
#define Dd 512
#define Hd 1024
#define Ld 20
#define Md (Bd*Td)   // 24000 rows

using f32x4  = __attribute__((ext_vector_type(4))) float;
using short8 = __attribute__((ext_vector_type(8))) short;

__device__ __forceinline__ unsigned short f2bf(float f) {
    union { float f; unsigned u; } v; v.f = f;
    unsigned r = v.u + 0x7fffu + ((v.u >> 16) & 1u);   // RNE
    return (unsigned short)(r >> 16);
}

// ---------------------------------------------------------------------------
// W [K][N] fp32  ->  WT [N][K] bf16   (32x32 LDS tile transpose)
// ---------------------------------------------------------------------------
__global__ __launch_bounds__(256) void transpose_convert_k(
    const float* __restrict__ W, unsigned short* __restrict__ WT, int K, int N)
{
    __shared__ float tile[32][33];
    int n0 = blockIdx.x * 32, k0 = blockIdx.y * 32;
    int tx = threadIdx.x, ty = threadIdx.y;   // 32 x 8
#pragma unroll
    for (int j = 0; j < 32; j += 8)
        tile[ty + j][tx] = W[(size_t)(k0 + ty + j) * N + n0 + tx];
    __syncthreads();
#pragma unroll
    for (int j = 0; j < 32; j += 8)
        WT[(size_t)(n0 + ty + j) * K + k0 + tx] = f2bf(tile[tx][ty + j]);
}

// ---------------------------------------------------------------------------
// C[M][N] = act(A[M][K] @ BT[N][K]^T + bias)
// BM=128 BN=128 BK=32, 256 threads (4 waves, 2x2 of 64x64), mfma 16x16x32 bf16
// ---------------------------------------------------------------------------
template<bool A_F32, bool RELU_BIAS, bool OUT_BF16>
__global__ __launch_bounds__(256) void gemm_bt(
    const void* __restrict__ Av, const unsigned short* __restrict__ BT,
    const float* __restrict__ bias, void* __restrict__ Cv,
    int Mdim, int Ndim, int Kdim)
{
    __shared__ unsigned short As[128][40];   // +8 pad: conflict-free frag reads
    __shared__ unsigned short Bs[128][40];   // stored as [n][k]

    const int tid  = threadIdx.x;
    const int lane = tid & 63;
    const int wave = tid >> 6;
    const int wr   = wave >> 1, wc = wave & 1;
    const int m0   = blockIdx.y * 128, n0 = blockIdx.x * 128;

    const int sRow  = tid >> 1;       // 0..127
    const int sHalf = tid & 1;        // k offset 0 / 16

    f32x4 acc[4][4] = {};

    for (int kk = 0; kk < Kdim; kk += 32) {
        // ---- global -> regs (issued before barrier to overlap) ----
        int4 bv0, bv1;
        {
            const int4* bp = (const int4*)(BT + (size_t)(n0 + sRow) * Kdim + kk + sHalf * 16);
            bv0 = bp[0]; bv1 = bp[1];
        }
        union { unsigned short us[16]; int4 v4[2]; } apk;
        if (A_F32) {
            const float* A = (const float*)Av;
            int gr = m0 + sRow; if (gr > Mdim - 1) gr = Mdim - 1;
            const float4* ap = (const float4*)(A + (size_t)gr * Kdim + kk + sHalf * 16);
            float fv[16];
#pragma unroll
            for (int q = 0; q < 4; ++q) {
                float4 t = ap[q];
                fv[4*q+0] = t.x; fv[4*q+1] = t.y; fv[4*q+2] = t.z; fv[4*q+3] = t.w;
            }
#pragma unroll
            for (int i = 0; i < 16; ++i) apk.us[i] = f2bf(fv[i]);
        } else {
            const unsigned short* A = (const unsigned short*)Av;
            int gr = m0 + sRow; if (gr > Mdim - 1) gr = Mdim - 1;
            const int4* ap = (const int4*)(A + (size_t)gr * Kdim + kk + sHalf * 16);
            apk.v4[0] = ap[0]; apk.v4[1] = ap[1];
        }

        __syncthreads();   // previous iteration's compute done
        *(int4*)&As[sRow][sHalf * 16 + 0] = apk.v4[0];
        *(int4*)&As[sRow][sHalf * 16 + 8] = apk.v4[1];
        *(int4*)&Bs[sRow][sHalf * 16 + 0] = bv0;
        *(int4*)&Bs[sRow][sHalf * 16 + 8] = bv1;
        __syncthreads();

        // ---- fragments + MFMA ----
        const int kgrp = (lane >> 4) * 8;
        const int rsel = lane & 15;
        short8 af[4], bf[4];
#pragma unroll
        for (int m = 0; m < 4; ++m)
            af[m] = *(const short8*)&As[wr * 64 + m * 16 + rsel][kgrp];
#pragma unroll
        for (int n = 0; n < 4; ++n)
            bf[n] = *(const short8*)&Bs[wc * 64 + n * 16 + rsel][kgrp];
#pragma unroll
        for (int m = 0; m < 4; ++m)
#pragma unroll
            for (int n = 0; n < 4; ++n)
                acc[m][n] = __builtin_amdgcn_mfma_f32_16x16x32_bf16(af[m], bf[n], acc[m][n], 0, 0, 0);
    }

    // ---- epilogue: C/D layout col=lane&15, row=(lane>>4)*4+j ----
    const int colBase = n0 + wc * 64;
    const int rowBase = m0 + wr * 64 + ((lane >> 4) << 2);
#pragma unroll
    for (int n = 0; n < 4; ++n) {
        const int col = colBase + n * 16 + (lane & 15);
        float bvs = 0.f;
        if (RELU_BIAS) bvs = bias[col];
#pragma unroll
        for (int m = 0; m < 4; ++m) {
            const int row = rowBase + m * 16;
#pragma unroll
            for (int j = 0; j < 4; ++j) {
                const int r = row + j;
                if (r < Mdim) {
                    float v = acc[m][n][j];
                    if (RELU_BIAS) v = fmaxf(v + bvs, 0.f);
                    if (OUT_BF16)
                        ((unsigned short*)Cv)[(size_t)r * Ndim + col] = f2bf(v);
                    else
                        ((float*)Cv)[(size_t)r * Ndim + col] = v;
                }
            }
        }
    }
}

// ---------------------------------------------------------------------------
// att[row][l] = softmax_l( x[row,:] @ wa[:,l] )   16 rows/block, 320 threads
// ---------------------------------------------------------------------------
__global__ __launch_bounds__(320) void att_kernel(
    const float* __restrict__ x, const float* __restrict__ wa,
    float* __restrict__ att)
{
    __shared__ float waS[Dd * Ld];        // [512][20] flat, 40KB
    __shared__ float sS[16][Ld];
    __shared__ float mS[16], iS[16];

    const int tid = threadIdx.x;
    for (int i = tid; i < Dd * Ld; i += 320) waS[i] = wa[i];

    const int r = tid / Ld;               // 0..15
    const int l = tid % Ld;               // 0..19
    const int row = blockIdx.x * 16 + r;
    const float* xr = x + (size_t)row * Dd;
    __syncthreads();

    float a0 = 0.f, a1 = 0.f, a2 = 0.f, a3 = 0.f;
#pragma unroll 4
    for (int d = 0; d < Dd; d += 4) {
        a0 += xr[d + 0] * waS[(d + 0) * Ld + l];
        a1 += xr[d + 1] * waS[(d + 1) * Ld + l];
        a2 += xr[d + 2] * waS[(d + 2) * Ld + l];
        a3 += xr[d + 3] * waS[(d + 3) * Ld + l];
    }
    sS[r][l] = (a0 + a1) + (a2 + a3);
    __syncthreads();

    if (tid < 16) {
        float m = -1e30f;
#pragma unroll
        for (int q = 0; q < Ld; ++q) m = fmaxf(m, sS[tid][q]);
        float s = 0.f;
#pragma unroll
        for (int q = 0; q < Ld; ++q) s += expf(sS[tid][q] - m);
        mS[tid] = m; iS[tid] = 1.f / s;
    }
    __syncthreads();
    att[(size_t)row * Ld + l] = expf(sS[r][l] - mS[r]) * iS[r];
}

// ---------------------------------------------------------------------------
// out[row][d] = x[row][d] + sum_i att[row][i] * p1[row-i][d]   (i <= t)
// ---------------------------------------------------------------------------
__global__ __launch_bounds__(128) void out_kernel(
    const float* __restrict__ x, const float* __restrict__ p1,
    const float* __restrict__ att, float* __restrict__ out)
{
    __shared__ float aS[Ld];
    const int row = blockIdx.x;
    const int t = row % Td;
    const int d4 = threadIdx.x;           // 0..127 -> float4

    if (threadIdx.x < Ld) aS[threadIdx.x] = att[(size_t)row * Ld + threadIdx.x];
    __syncthreads();

    float4 acc = ((const float4*)(x + (size_t)row * Dd))[d4];
    const int imax = (t < Ld - 1) ? t : (Ld - 1);
    for (int i = 0; i <= imax; ++i) {
        const float c = aS[i];
        float4 p = ((const float4*)(p1 + (size_t)(row - i) * Dd))[d4];
        acc.x += c * p.x; acc.y += c * p.y; acc.z += c * p.z; acc.w += c * p.w;
    }
    ((float4*)out)[(size_t)row * (Dd / 4) + d4] = acc;
}

// ---------------------------------------------------------------------------
extern "C" void kernel_launch(void* const* d_in, const int* in_sizes, int n_in,
                              void* d_out, int out_size, void* d_ws, size_t ws_size,
                              hipStream_t stream)
{
    const float* x  = (const float*)d_in[0];
    const float* w1 = (const float*)d_in[1];
    const float* b1 = (const float*)d_in[2];
    const float* wp = (const float*)d_in[3];
    const float* wa = (const float*)d_in[4];
    float* out = (float*)d_out;

    char* ws = (char*)d_ws;
    unsigned short* w1T = (unsigned short*)ws;            ws += (size_t)Hd * Dd * 2;   // [H][D] bf16
    unsigned short* wpT = (unsigned short*)ws;            ws += (size_t)Dd * Hd * 2;   // [D][H] bf16
    unsigned short* f1  = (unsigned short*)ws;            ws += (size_t)Md * Hd * 2;   // [M][H] bf16
    float*          p1  = (float*)ws;                     ws += (size_t)Md * Dd * 4;   // [M][D] f32
    float*          att = (float*)ws;                     ws += (size_t)Md * Ld * 4;   // [M][L] f32

    // weight transpose+convert:  w1 [D][H] -> w1T [H][D],  wp [H][D] -> wpT [D][H]
    transpose_convert_k<<<dim3(Hd / 32, Dd / 32), dim3(32, 8), 0, stream>>>(w1, w1T, Dd, Hd);
    transpose_convert_k<<<dim3(Dd / 32, Hd / 32), dim3(32, 8), 0, stream>>>(wp, wpT, Hd, Dd);

    const int mtiles = (Md + 127) / 128;   // 188
    // f1 = relu(x @ w1 + b1)  -> bf16
    gemm_bt<true, true, true><<<dim3(Hd / 128, mtiles), 256, 0, stream>>>(
        (const void*)x, w1T, b1, (void*)f1, Md, Hd, Dd);
    // p1 = f1 @ wp  -> f32
    gemm_bt<false, false, false><<<dim3(Dd / 128, mtiles), 256, 0, stream>>>(
        (const void*)f1, wpT, nullptr, (void*)p1, Md, Dd, Hd);

    // att = softmax(x @ wa)
    att_kernel<<<Md / 16, 320, 0, stream>>>(x, wa, att);

    // out = x + sum_i att_i * p1[t-i]
    out_kernel<<<Md, 128, 0, stream>>>(x, p1, att, out);
}

// Round 2
// 277.731 us; speedup vs baseline: 1.4060x; 1.4060x over previous
//
#include <hip/hip_runtime.h>
#include <hip/hip_bf16.h>

#define Bd 16
#define Td 1500
#define Dd 512
#define Hd 1024
#define Ld 20
#define Md (Bd*Td)   // 24000 rows

using f32x4  = __attribute__((ext_vector_type(4))) float;
using short8 = __attribute__((ext_vector_type(8))) short;

__device__ __forceinline__ unsigned short f2bf(float f) {
    union { float f; unsigned u; } v; v.f = f;
    unsigned r = v.u + 0x7fffu + ((v.u >> 16) & 1u);   // RNE
    return (unsigned short)(r >> 16);
}
__device__ __forceinline__ float bf2f(unsigned short u) {
    union { unsigned u; float f; } v; v.u = ((unsigned)u) << 16;
    return v.f;
}
__device__ __forceinline__ void gload_lds16(const void* g, void* l) {
    __builtin_amdgcn_global_load_lds(
        (const __attribute__((address_space(1))) unsigned*)g,
        (__attribute__((address_space(3))) unsigned*)l, 16, 0, 0);
}

// ---------------------------------------------------------------------------
// x fp32 -> bf16 (8 elems/thread)
// ---------------------------------------------------------------------------
__global__ __launch_bounds__(256) void cvt_x_kernel(
    const float* __restrict__ in, unsigned short* __restrict__ out)
{
    size_t i = ((size_t)blockIdx.x * 256 + threadIdx.x) * 8;
    float4 v0 = *(const float4*)(in + i);
    float4 v1 = *(const float4*)(in + i + 4);
    union { unsigned short us[8]; int4 v; } p;
    p.us[0] = f2bf(v0.x); p.us[1] = f2bf(v0.y); p.us[2] = f2bf(v0.z); p.us[3] = f2bf(v0.w);
    p.us[4] = f2bf(v1.x); p.us[5] = f2bf(v1.y); p.us[6] = f2bf(v1.z); p.us[7] = f2bf(v1.w);
    *(int4*)(out + i) = p.v;
}

// ---------------------------------------------------------------------------
// W [K][N] fp32  ->  WT [N][K] bf16   (32x32 LDS tile transpose)
// ---------------------------------------------------------------------------
__global__ __launch_bounds__(256) void transpose_convert_k(
    const float* __restrict__ W, unsigned short* __restrict__ WT, int K, int N)
{
    __shared__ float tile[32][33];
    int n0 = blockIdx.x * 32, k0 = blockIdx.y * 32;
    int tx = threadIdx.x, ty = threadIdx.y;   // 32 x 8
#pragma unroll
    for (int j = 0; j < 32; j += 8)
        tile[ty + j][tx] = W[(size_t)(k0 + ty + j) * N + n0 + tx];
    __syncthreads();
#pragma unroll
    for (int j = 0; j < 32; j += 8)
        WT[(size_t)(n0 + ty + j) * K + k0 + tx] = f2bf(tile[tx][ty + j]);
}

// ---------------------------------------------------------------------------
// C[M][N] = act(A[M][K] @ BT[N][K]^T + bias)   A,BT bf16, C bf16
// BM=BN=128, BK=32, 256 threads (4 waves 2x2 of 64x64), mfma 16x16x32 bf16
// Staging: global_load_lds dwordx4, linear LDS [128][32] (conflict-free:
// a wave's 8 frag ds_read_b128 cover a contiguous 1KiB block).
// ---------------------------------------------------------------------------
template<bool RELU_BIAS>
__global__ __launch_bounds__(256) void gemm_lds(
    const unsigned short* __restrict__ A, const unsigned short* __restrict__ BT,
    const float* __restrict__ bias, unsigned short* __restrict__ C,
    int Mdim, int Ndim, int Kdim)
{
    __shared__ __align__(16) unsigned short As[128 * 32];
    __shared__ __align__(16) unsigned short Bs[128 * 32];

    const int tid  = threadIdx.x;
    const int lane = tid & 63;
    const int wave = tid >> 6;
    const int wr   = wave >> 1, wc = wave & 1;

    // chunked XCD swizzle (nwg % 8 == 0 for both GEMMs)
    const int nx  = gridDim.x;
    const int nwg = nx * gridDim.y;
    const int id  = blockIdx.y * nx + blockIdx.x;
    const int nid = (id & 7) * (nwg >> 3) + (id >> 3);
    const int m0  = (nid / nx) * 128;
    const int n0  = (nid % nx) * 128;

    // staging coords: tid covers 64 rows x 4 slots of 16B per round
    const int srow  = tid >> 2;     // 0..63
    const int sslot = tid & 3;      // k-slot (8 bf16 = 16B)
    int ar0 = m0 + srow;      if (ar0 >= Mdim) ar0 = Mdim - 1;
    int ar1 = m0 + 64 + srow; if (ar1 >= Mdim) ar1 = Mdim - 1;
    const unsigned short* a0p = A  + (size_t)ar0 * Kdim + sslot * 8;
    const unsigned short* a1p = A  + (size_t)ar1 * Kdim + sslot * 8;
    const unsigned short* b0p = BT + (size_t)(n0 + srow) * Kdim + sslot * 8;
    const unsigned short* b1p = BT + (size_t)(n0 + 64 + srow) * Kdim + sslot * 8;

    // wave-uniform LDS dest bases (HW writes lane i at base + i*16B)
    unsigned short* asD0 = As + wave * 512;
    unsigned short* asD1 = As + 2048 + wave * 512;
    unsigned short* bsD0 = Bs + wave * 512;
    unsigned short* bsD1 = Bs + 2048 + wave * 512;

    const int kgrp = (lane >> 4) * 8;   // element offset within row
    const int rsel = lane & 15;

    f32x4 acc[4][4] = {};

    for (int kk = 0; kk < Kdim; kk += 32) {
        __syncthreads();                       // prev tile fully consumed
        gload_lds16(a0p + kk, asD0);
        gload_lds16(a1p + kk, asD1);
        gload_lds16(b0p + kk, bsD0);
        gload_lds16(b1p + kk, bsD1);
        __syncthreads();                       // vmcnt(0) drain -> tile ready

        short8 af[4], bfr[4];
#pragma unroll
        for (int m = 0; m < 4; ++m)
            af[m] = *(const short8*)&As[(wr * 64 + m * 16 + rsel) * 32 + kgrp];
#pragma unroll
        for (int n = 0; n < 4; ++n)
            bfr[n] = *(const short8*)&Bs[(wc * 64 + n * 16 + rsel) * 32 + kgrp];
#pragma unroll
        for (int m = 0; m < 4; ++m)
#pragma unroll
            for (int n = 0; n < 4; ++n)
                acc[m][n] = __builtin_amdgcn_mfma_f32_16x16x32_bf16(af[m], bfr[n], acc[m][n], 0, 0, 0);
    }

    // epilogue: C/D layout col=lane&15, row=(lane>>4)*4+j
    const int colBase = n0 + wc * 64;
    const int rowBase = m0 + wr * 64 + ((lane >> 4) << 2);
#pragma unroll
    for (int n = 0; n < 4; ++n) {
        const int col = colBase + n * 16 + (lane & 15);
        float bvs = 0.f;
        if (RELU_BIAS) bvs = bias[col];
#pragma unroll
        for (int m = 0; m < 4; ++m) {
#pragma unroll
            for (int j = 0; j < 4; ++j) {
                const int r = rowBase + m * 16 + j;
                if (r < Mdim) {
                    float v = acc[m][n][j];
                    if (RELU_BIAS) v = fmaxf(v + bvs, 0.f);
                    C[(size_t)r * Ndim + col] = f2bf(v);
                }
            }
        }
    }
}

// ---------------------------------------------------------------------------
// att[row][l] = softmax_l( x[row,:] @ wa[:,l] )
// 12 rows/block, 256 threads; x + wa staged in LDS (x rows padded stride 513)
// ---------------------------------------------------------------------------
__global__ __launch_bounds__(256) void att_kernel(
    const float* __restrict__ x, const float* __restrict__ wa,
    float* __restrict__ att)
{
    __shared__ float waS[Dd * Ld];      // 40 KB
    __shared__ float xs[12 * 513];      // 24.6 KB, stride 513 breaks bank alias
    __shared__ float sS[12][Ld];
    __shared__ float mS[12], iS[12];

    const int tid  = threadIdx.x;
    const int row0 = blockIdx.x * 12;

    for (int i = tid * 4; i < Dd * Ld; i += 1024)
        *(float4*)&waS[i] = *(const float4*)&wa[i];
    for (int i = tid * 4; i < 12 * Dd; i += 1024) {
        int r = i >> 9, d = i & 511;
        float4 v = *(const float4*)&x[(size_t)(row0 + r) * Dd + d];
        xs[r * 513 + d]     = v.x; xs[r * 513 + d + 1] = v.y;
        xs[r * 513 + d + 2] = v.z; xs[r * 513 + d + 3] = v.w;
    }
    __syncthreads();

    const int r = tid / Ld, l = tid % Ld;   // active: tid < 240
    float s = 0.f;
    if (tid < 240) {
        const float* xr = &xs[r * 513];
        float a0 = 0.f, a1 = 0.f, a2 = 0.f, a3 = 0.f;
#pragma unroll 8
        for (int d = 0; d < Dd; d += 4) {
            a0 += xr[d + 0] * waS[(d + 0) * Ld + l];
            a1 += xr[d + 1] * waS[(d + 1) * Ld + l];
            a2 += xr[d + 2] * waS[(d + 2) * Ld + l];
            a3 += xr[d + 3] * waS[(d + 3) * Ld + l];
        }
        s = (a0 + a1) + (a2 + a3);
        sS[r][l] = s;
    }
    __syncthreads();
    if (tid < 12) {
        float m = -1e30f;
#pragma unroll
        for (int q = 0; q < Ld; ++q) m = fmaxf(m, sS[tid][q]);
        float sum = 0.f;
#pragma unroll
        for (int q = 0; q < Ld; ++q) sum += __expf(sS[tid][q] - m);
        mS[tid] = m; iS[tid] = 1.f / sum;
    }
    __syncthreads();
    if (tid < 240)
        att[(size_t)(row0 + r) * Ld + l] = __expf(s - mS[r]) * iS[r];
}

// ---------------------------------------------------------------------------
// out[row][d] = x[row][d] + sum_i att[row][i] * p1[row-i][d]
// 4 rows/block (1 wave/row), p1 bf16, 8 elems/lane
// ---------------------------------------------------------------------------
__global__ __launch_bounds__(256) void out_kernel(
    const float* __restrict__ x, const unsigned short* __restrict__ p1,
    const float* __restrict__ att, float* __restrict__ out)
{
    const int lane = threadIdx.x & 63;
    const int row  = blockIdx.x * 4 + (threadIdx.x >> 6);
    const int t    = row % Td;
    const int d0   = lane * 8;

    const float* xr = x + (size_t)row * Dd + d0;
    float4 xa = *(const float4*)xr;
    float4 xb = *(const float4*)(xr + 4);
    float acc[8] = { xa.x, xa.y, xa.z, xa.w, xb.x, xb.y, xb.z, xb.w };

    const int imax = (t < Ld - 1) ? t : (Ld - 1);
    const float* ar = att + (size_t)row * Ld;
    const unsigned short* pr = p1 + (size_t)row * Dd + d0;
    for (int i = 0; i <= imax; ++i) {
        float a = ar[i];
        short8 p = *(const short8*)(pr - (size_t)i * Dd);
#pragma unroll
        for (int j = 0; j < 8; ++j) acc[j] += a * bf2f((unsigned short)p[j]);
    }
    float* orow = out + (size_t)row * Dd + d0;
    float4 o0 = { acc[0], acc[1], acc[2], acc[3] };
    float4 o1 = { acc[4], acc[5], acc[6], acc[7] };
    *(float4*)orow       = o0;
    *(float4*)(orow + 4) = o1;
}

// ---------------------------------------------------------------------------
extern "C" void kernel_launch(void* const* d_in, const int* in_sizes, int n_in,
                              void* d_out, int out_size, void* d_ws, size_t ws_size,
                              hipStream_t stream)
{
    const float* x  = (const float*)d_in[0];
    const float* w1 = (const float*)d_in[1];
    const float* b1 = (const float*)d_in[2];
    const float* wp = (const float*)d_in[3];
    const float* wa = (const float*)d_in[4];
    float* out = (float*)d_out;

    char* ws = (char*)d_ws;
    unsigned short* xb  = (unsigned short*)ws;  ws += (size_t)Md * Dd * 2;   // [M][D] bf16
    unsigned short* w1T = (unsigned short*)ws;  ws += (size_t)Hd * Dd * 2;   // [H][D] bf16
    unsigned short* wpT = (unsigned short*)ws;  ws += (size_t)Dd * Hd * 2;   // [D][H] bf16
    unsigned short* f1  = (unsigned short*)ws;  ws += (size_t)Md * Hd * 2;   // [M][H] bf16
    unsigned short* p1  = (unsigned short*)ws;  ws += (size_t)Md * Dd * 2;   // [M][D] bf16
    float*          att = (float*)ws;           ws += (size_t)Md * Ld * 4;   // [M][L] f32

    cvt_x_kernel<<<(Md * Dd) / 2048, 256, 0, stream>>>(x, xb);
    transpose_convert_k<<<dim3(Hd / 32, Dd / 32), dim3(32, 8), 0, stream>>>(w1, w1T, Dd, Hd);
    transpose_convert_k<<<dim3(Dd / 32, Hd / 32), dim3(32, 8), 0, stream>>>(wp, wpT, Hd, Dd);

    att_kernel<<<Md / 12, 256, 0, stream>>>(x, wa, att);

    const int mtiles = (Md + 127) / 128;   // 188
    gemm_lds<true ><<<dim3(Hd / 128, mtiles), 256, 0, stream>>>(xb, w1T, b1, f1, Md, Hd, Dd);
    gemm_lds<false><<<dim3(Dd / 128, mtiles), 256, 0, stream>>>(f1, wpT, nullptr, p1, Md, Dd, Hd);

    out_kernel<<<Md / 4, 256, 0, stream>>>(x, p1, att, out);
}

// Round 3
// 226.147 us; speedup vs baseline: 1.7268x; 1.2281x over previous
//
#include <hip/hip_runtime.h>
#include <hip/hip_bf16.h>

#define Bd 16
#define Td 1500
#define Dd 512
#define Hd 1024
#define Ld 20
#define Md (Bd*Td)   // 24000 rows

using f32x4  = __attribute__((ext_vector_type(4))) float;
using short8 = __attribute__((ext_vector_type(8))) short;

__device__ __forceinline__ unsigned short f2bf(float f) {
    union { float f; unsigned u; } v; v.f = f;
    unsigned r = v.u + 0x7fffu + ((v.u >> 16) & 1u);   // RNE
    return (unsigned short)(r >> 16);
}
__device__ __forceinline__ float bf2f(unsigned short u) {
    union { unsigned u; float f; } v; v.u = ((unsigned)u) << 16;
    return v.f;
}
__device__ __forceinline__ void gload_lds16(const void* g, void* l) {
    __builtin_amdgcn_global_load_lds(
        (const __attribute__((address_space(1))) unsigned*)g,
        (__attribute__((address_space(3))) unsigned*)l, 16, 0, 0);
}

// ---------------------------------------------------------------------------
// x fp32 -> bf16 (8 elems/thread)
// ---------------------------------------------------------------------------
__global__ __launch_bounds__(256) void cvt_x_kernel(
    const float* __restrict__ in, unsigned short* __restrict__ out)
{
    size_t i = ((size_t)blockIdx.x * 256 + threadIdx.x) * 8;
    float4 v0 = *(const float4*)(in + i);
    float4 v1 = *(const float4*)(in + i + 4);
    union { unsigned short us[8]; int4 v; } p;
    p.us[0] = f2bf(v0.x); p.us[1] = f2bf(v0.y); p.us[2] = f2bf(v0.z); p.us[3] = f2bf(v0.w);
    p.us[4] = f2bf(v1.x); p.us[5] = f2bf(v1.y); p.us[6] = f2bf(v1.z); p.us[7] = f2bf(v1.w);
    *(int4*)(out + i) = p.v;
}

// ---------------------------------------------------------------------------
// W [K][N] fp32 -> WT [N][K] bf16
// ---------------------------------------------------------------------------
__global__ __launch_bounds__(256) void transpose_convert_k(
    const float* __restrict__ W, unsigned short* __restrict__ WT, int K, int N)
{
    __shared__ float tile[32][33];
    int n0 = blockIdx.x * 32, k0 = blockIdx.y * 32;
    int tx = threadIdx.x, ty = threadIdx.y;   // 32 x 8
#pragma unroll
    for (int j = 0; j < 32; j += 8)
        tile[ty + j][tx] = W[(size_t)(k0 + ty + j) * N + n0 + tx];
    __syncthreads();
#pragma unroll
    for (int j = 0; j < 32; j += 8)
        WT[(size_t)(n0 + ty + j) * K + k0 + tx] = f2bf(tile[tx][ty + j]);
}

// ---------------------------------------------------------------------------
// waT[32][512] bf16: waT[c][d] = wa[d][c] (c<20), else 0
// ---------------------------------------------------------------------------
__global__ __launch_bounds__(256) void prep_waT_kernel(
    const float* __restrict__ wa, unsigned short* __restrict__ waT)
{
    int i = blockIdx.x * 256 + threadIdx.x;   // 0..16383
    int c = i >> 9, d = i & 511;
    waT[i] = (c < Ld) ? f2bf(wa[(size_t)d * Ld + c]) : (unsigned short)0;
}

// ---------------------------------------------------------------------------
// C[M][N] = act(A[M][K] @ BT[N][K]^T + bias)   A,BT,C bf16
// BM=BN=128, BK=32, 4 waves (2x2 of 64x64), mfma 16x16x32 bf16
// 2-phase prefetch double-buffer; XOR k-slot swizzle (sigma(r)=(r>>1)&3)
// applied to the gload_lds GLOBAL source and the ds_read offset.
// ---------------------------------------------------------------------------
template<bool RELU_BIAS>
__global__ __launch_bounds__(256) void gemm_lds(
    const unsigned short* __restrict__ A, const unsigned short* __restrict__ BT,
    const float* __restrict__ bias, unsigned short* __restrict__ C,
    int Mdim, int Ndim, int Kdim)
{
    __shared__ __align__(16) unsigned short As[2 * 128 * 32];
    __shared__ __align__(16) unsigned short Bs[2 * 128 * 32];

    const int tid  = threadIdx.x;
    const int lane = tid & 63;
    const int wave = tid >> 6;
    const int wr   = wave >> 1, wc = wave & 1;

    // chunked XCD swizzle (nwg % 8 == 0 for both GEMMs)
    const int nx  = gridDim.x;
    const int nwg = nx * gridDim.y;
    const int id  = blockIdx.y * nx + blockIdx.x;
    const int nid = (id & 7) * (nwg >> 3) + (id >> 3);
    const int m0  = (nid / nx) * 128;
    const int n0  = (nid % nx) * 128;

    // staging: thread covers (row = tid>>2, 16B k-slot = swizzled tid&3)
    const int srow  = tid >> 2;                       // 0..63
    const int sslot = (tid & 3) ^ ((tid >> 3) & 3);   // inverse-swizzled source
    int ar0 = m0 + srow;      if (ar0 >= Mdim) ar0 = Mdim - 1;
    int ar1 = m0 + 64 + srow; if (ar1 >= Mdim) ar1 = Mdim - 1;
    const unsigned short* a0p = A  + (size_t)ar0 * Kdim + sslot * 8;
    const unsigned short* a1p = A  + (size_t)ar1 * Kdim + sslot * 8;
    const unsigned short* b0p = BT + (size_t)(n0 + srow) * Kdim + sslot * 8;
    const unsigned short* b1p = BT + (size_t)(n0 + 64 + srow) * Kdim + sslot * 8;

    const int rsel = lane & 15;
    const int koff = ((lane >> 4) ^ ((lane >> 1) & 3)) * 8;   // swizzled read slot

    f32x4 acc[4][4] = {};

    const int NT = Kdim >> 5;

    // prologue: stage tile 0 into buf 0
    gload_lds16(a0p, As + wave * 512);
    gload_lds16(a1p, As + 2048 + wave * 512);
    gload_lds16(b0p, Bs + wave * 512);
    gload_lds16(b1p, Bs + 2048 + wave * 512);
    __syncthreads();   // drains vmcnt(0): tile 0 ready

    for (int t = 0; t < NT; ++t) {
        const int cur = t & 1;
        if (t + 1 < NT) {          // issue next-tile loads (land before next barrier)
            const int kk = (t + 1) * 32;
            unsigned short* as = As + (cur ^ 1) * 4096;
            unsigned short* bs = Bs + (cur ^ 1) * 4096;
            gload_lds16(a0p + kk, as + wave * 512);
            gload_lds16(a1p + kk, as + 2048 + wave * 512);
            gload_lds16(b0p + kk, bs + wave * 512);
            gload_lds16(b1p + kk, bs + 2048 + wave * 512);
        }
        const unsigned short* as = As + cur * 4096;
        const unsigned short* bs = Bs + cur * 4096;
        short8 af[4], bfr[4];
#pragma unroll
        for (int m = 0; m < 4; ++m)
            af[m] = *(const short8*)&as[(wr * 64 + m * 16 + rsel) * 32 + koff];
#pragma unroll
        for (int n = 0; n < 4; ++n)
            bfr[n] = *(const short8*)&bs[(wc * 64 + n * 16 + rsel) * 32 + koff];
#pragma unroll
        for (int m = 0; m < 4; ++m)
#pragma unroll
            for (int n = 0; n < 4; ++n)
                acc[m][n] = __builtin_amdgcn_mfma_f32_16x16x32_bf16(af[m], bfr[n], acc[m][n], 0, 0, 0);
        __syncthreads();           // drain this iter's stage + sync buffers
    }

    // epilogue: C/D layout col=lane&15, row=(lane>>4)*4+j
    const int colBase = n0 + wc * 64;
    const int rowBase = m0 + wr * 64 + ((lane >> 4) << 2);
#pragma unroll
    for (int n = 0; n < 4; ++n) {
        const int col = colBase + n * 16 + (lane & 15);
        float bvs = 0.f;
        if (RELU_BIAS) bvs = bias[col];
#pragma unroll
        for (int m = 0; m < 4; ++m) {
#pragma unroll
            for (int j = 0; j < 4; ++j) {
                const int r = rowBase + m * 16 + j;
                if (r < Mdim) {
                    float v = acc[m][n][j];
                    if (RELU_BIAS) v = fmaxf(v + bvs, 0.f);
                    C[(size_t)r * Ndim + col] = f2bf(v);
                }
            }
        }
    }
}

// ---------------------------------------------------------------------------
// att[row][l] = softmax_l( xb[row,:] @ waT[l,:]^T )  via MFMA
// 128 rows/block, 4 waves; waT staged whole (16 swizzled [32][32] K-tiles);
// A (xb) double-buffered via gload_lds; softmax in epilogue through LDS.
// ---------------------------------------------------------------------------
__global__ __launch_bounds__(256) void att_mfma_kernel(
    const unsigned short* __restrict__ xb, const unsigned short* __restrict__ waT,
    float* __restrict__ att)
{
    __shared__ __align__(16) unsigned short waTs[16 * 1024];  // 32KB
    __shared__ __align__(16) unsigned short As[2 * 128 * 32]; // 16KB
    __shared__ float sS[128][33];                             // 16.9KB

    const int tid  = threadIdx.x;
    const int lane = tid & 63;
    const int wave = tid >> 6;
    const int m0   = blockIdx.x * 128;

    // stage waTs: dest linear-tiled [kt][c][slot'], source slot = slot'^sigma(c)
    for (int i = tid; i < 2048; i += 256) {
        const int off = i * 8;
        const int kt = off >> 10, c = (off >> 5) & 31, sl = (off >> 3) & 3;
        const int ssl = sl ^ ((c >> 1) & 3);
        *(short8*)&waTs[off] = *(const short8*)&waT[(size_t)c * Dd + kt * 32 + ssl * 8];
    }

    const int srow  = tid >> 2;
    const int sslot = (tid & 3) ^ ((tid >> 3) & 3);
    int ar0 = m0 + srow;      if (ar0 >= Md) ar0 = Md - 1;
    int ar1 = m0 + 64 + srow; if (ar1 >= Md) ar1 = Md - 1;
    const unsigned short* a0p = xb + (size_t)ar0 * Dd + sslot * 8;
    const unsigned short* a1p = xb + (size_t)ar1 * Dd + sslot * 8;

    const int rsel = lane & 15;
    const int koff = ((lane >> 4) ^ ((lane >> 1) & 3)) * 8;

    f32x4 acc[2][2] = {};

    gload_lds16(a0p, As + wave * 512);
    gload_lds16(a1p, As + 2048 + wave * 512);
    __syncthreads();

    for (int t = 0; t < 16; ++t) {
        const int cur = t & 1;
        if (t + 1 < 16) {
            unsigned short* as = As + (cur ^ 1) * 4096;
            gload_lds16(a0p + (t + 1) * 32, as + wave * 512);
            gload_lds16(a1p + (t + 1) * 32, as + 2048 + wave * 512);
        }
        const unsigned short* as = As + cur * 4096;
        short8 af[2], bfr[2];
#pragma unroll
        for (int m = 0; m < 2; ++m)
            af[m] = *(const short8*)&as[(wave * 32 + m * 16 + rsel) * 32 + koff];
#pragma unroll
        for (int n = 0; n < 2; ++n)
            bfr[n] = *(const short8*)&waTs[t * 1024 + (n * 16 + rsel) * 32 + koff];
#pragma unroll
        for (int m = 0; m < 2; ++m)
#pragma unroll
            for (int n = 0; n < 2; ++n)
                acc[m][n] = __builtin_amdgcn_mfma_f32_16x16x32_bf16(af[m], bfr[n], acc[m][n], 0, 0, 0);
        __syncthreads();
    }

    // logits -> LDS (wave w owns rows w*32..w*32+31, cols 0..31)
    const int r0 = wave * 32 + ((lane >> 4) << 2);
#pragma unroll
    for (int m = 0; m < 2; ++m)
#pragma unroll
        for (int n = 0; n < 2; ++n)
#pragma unroll
            for (int j = 0; j < 4; ++j)
                sS[r0 + m * 16 + j][n * 16 + (lane & 15)] = acc[m][n][j];
    __syncthreads();

    if (tid < 128) {
        const int grow = m0 + tid;
        if (grow < Md) {
            float mx = -1e30f;
#pragma unroll
            for (int l = 0; l < Ld; ++l) mx = fmaxf(mx, sS[tid][l]);
            float e[Ld]; float sum = 0.f;
#pragma unroll
            for (int l = 0; l < Ld; ++l) { e[l] = __expf(sS[tid][l] - mx); sum += e[l]; }
            const float inv = 1.f / sum;
#pragma unroll
            for (int l = 0; l < Ld; ++l)
                att[(size_t)grow * Ld + l] = e[l] * inv;
        }
    }
}

// ---------------------------------------------------------------------------
// out[row][d] = x[row][d] + sum_i att[row][i] * p1[row-i][d]
// 8 rows/block (wave per row); XCD-chunked block mapping so each XCD's
// p1 window (~3MB) fits its private L2.
// ---------------------------------------------------------------------------
__global__ __launch_bounds__(512) void out_kernel(
    const float* __restrict__ x, const unsigned short* __restrict__ p1,
    const float* __restrict__ att, float* __restrict__ out)
{
    const int bid = blockIdx.x;                       // 3000
    const int nid = (bid & 7) * 375 + (bid >> 3);     // XCD-contiguous chunks
    const int wave = threadIdx.x >> 6;
    const int lane = threadIdx.x & 63;
    const int row  = nid * 8 + wave;
    const int t    = row % Td;
    const int d0   = lane * 8;

    float av[Ld];
    const float* ar = att + (size_t)row * Ld;
#pragma unroll
    for (int i = 0; i < Ld; i += 4) {
        float4 v = *(const float4*)(ar + i);
        av[i] = v.x; av[i + 1] = v.y; av[i + 2] = v.z; av[i + 3] = v.w;
    }

    const float* xr = x + (size_t)row * Dd + d0;
    float4 xa = *(const float4*)xr;
    float4 xb4 = *(const float4*)(xr + 4);
    float acc[8] = { xa.x, xa.y, xa.z, xa.w, xb4.x, xb4.y, xb4.z, xb4.w };

    const int imax = (t < Ld - 1) ? t : (Ld - 1);
    const unsigned short* pr = p1 + (size_t)row * Dd + d0;
    for (int i = 0; i <= imax; ++i) {
        const float a = av[i];
        short8 p = *(const short8*)(pr - (size_t)i * Dd);
#pragma unroll
        for (int j = 0; j < 8; ++j) acc[j] += a * bf2f((unsigned short)p[j]);
    }
    float* orow = out + (size_t)row * Dd + d0;
    float4 o0 = { acc[0], acc[1], acc[2], acc[3] };
    float4 o1 = { acc[4], acc[5], acc[6], acc[7] };
    *(float4*)orow       = o0;
    *(float4*)(orow + 4) = o1;
}

// ---------------------------------------------------------------------------
extern "C" void kernel_launch(void* const* d_in, const int* in_sizes, int n_in,
                              void* d_out, int out_size, void* d_ws, size_t ws_size,
                              hipStream_t stream)
{
    const float* x  = (const float*)d_in[0];
    const float* w1 = (const float*)d_in[1];
    const float* b1 = (const float*)d_in[2];
    const float* wp = (const float*)d_in[3];
    const float* wa = (const float*)d_in[4];
    float* out = (float*)d_out;

    char* ws = (char*)d_ws;
    unsigned short* xb  = (unsigned short*)ws;  ws += (size_t)Md * Dd * 2;   // bf16 x
    unsigned short* w1T = (unsigned short*)ws;  ws += (size_t)Hd * Dd * 2;
    unsigned short* wpT = (unsigned short*)ws;  ws += (size_t)Dd * Hd * 2;
    unsigned short* waT = (unsigned short*)ws;  ws += (size_t)32 * Dd * 2;
    unsigned short* f1  = (unsigned short*)ws;  ws += (size_t)Md * Hd * 2;
    unsigned short* p1  = (unsigned short*)ws;  ws += (size_t)Md * Dd * 2;
    float*          att = (float*)ws;           ws += (size_t)Md * Ld * 4;

    cvt_x_kernel<<<(Md * Dd) / 2048, 256, 0, stream>>>(x, xb);
    transpose_convert_k<<<dim3(Hd / 32, Dd / 32), dim3(32, 8), 0, stream>>>(w1, w1T, Dd, Hd);
    transpose_convert_k<<<dim3(Dd / 32, Hd / 32), dim3(32, 8), 0, stream>>>(wp, wpT, Hd, Dd);
    prep_waT_kernel<<<(32 * Dd) / 256, 256, 0, stream>>>(wa, waT);

    const int mtiles = (Md + 127) / 128;   // 188
    att_mfma_kernel<<<mtiles, 256, 0, stream>>>(xb, waT, att);

    gemm_lds<true ><<<dim3(Hd / 128, mtiles), 256, 0, stream>>>(xb, w1T, b1, f1, Md, Hd, Dd);
    gemm_lds<false><<<dim3(Dd / 128, mtiles), 256, 0, stream>>>(f1, wpT, nullptr, p1, Md, Dd, Hd);

    out_kernel<<<Md / 8, 512, 0, stream>>>(x, p1, att, out);
}